// Round 7
// baseline (168.145 us; speedup 1.0000x reference)
//
#include <hip/hip_runtime.h>
#include <hip/hip_bf16.h>

#define BD 4
#define CD 96
#define OD 96
#define HD 128
#define WD 128
#define HWD (HD*WD)          // 16384

typedef __attribute__((ext_vector_type(8))) short bfrag;   // 8 bf16 (4 VGPRs)
typedef __attribute__((ext_vector_type(4))) float ffrag;   // 4 fp32 acc

__device__ __forceinline__ short f2bs(float f) {
    __hip_bfloat16 h = __float2bfloat16(f);
    return *reinterpret_cast<short*>(&h);
}

// bilinear combine of 4 corner channel-fragments -> bf16 A-fragment
__device__ __forceinline__ bfrag interp4(bfrag c00, bfrag c01, bfrag c10, bfrag c11,
                                         float f00, float f01, float f10, float f11) {
    const int* i00 = (const int*)&c00;
    const int* i01 = (const int*)&c01;
    const int* i10 = (const int*)&c10;
    const int* i11 = (const int*)&c11;
    int ap[4];
    #pragma unroll
    for (int d = 0; d < 4; d++) {
        float a0 = __int_as_float(((unsigned)i00[d]) << 16);
        float b0 = __int_as_float(((unsigned)i01[d]) << 16);
        float c0 = __int_as_float(((unsigned)i10[d]) << 16);
        float d0 = __int_as_float(((unsigned)i11[d]) << 16);
        float a1 = __int_as_float(i00[d] & 0xffff0000);
        float b1 = __int_as_float(i01[d] & 0xffff0000);
        float c1 = __int_as_float(i10[d] & 0xffff0000);
        float d1 = __int_as_float(i11[d] & 0xffff0000);
        float rlo = f00*a0 + f01*b0 + f10*c0 + f11*d0;
        float rhi = f00*a1 + f01*b1 + f10*c1 + f11*d1;
        ap[d] = (int)((unsigned short)f2bs(rlo)) |
                ((int)((unsigned short)f2bs(rhi)) << 16);
    }
    return *(const bfrag*)ap;
}

// XCD-aware swizzle for 256-block grids: XCD k owns 32 consecutive logical
// blocks = half an image (64 rows) -> tap/gather halos stay in its L2.
__device__ __forceinline__ int swizzle256(int gid) {
    return ((gid & 7) << 5) | (gid >> 3);
}

// ---------------------------------------------------------------------------
// Transpose: x (NCHW fp32) -> xb16 (pixel-major NHWC bf16). 64 px/block.
// ---------------------------------------------------------------------------
__global__ __launch_bounds__(256) void k_transpose(const float* __restrict__ x,
                                                   short* __restrict__ xb16) {
    __shared__ short tile[64 * 104];
    int pix0 = blockIdx.x * 64;
    int b = pix0 / HWD; int hw0 = pix0 % HWD;
    int tid = threadIdx.x;

    for (int e = tid; e < 96*16; e += 256) {
        int c = e >> 4, g = e & 15;
        float4 v = *(const float4*)(x + ((size_t)(b*96 + c))*HWD + hw0 + 4*g);
        tile[(4*g+0)*104 + c] = f2bs(v.x);
        tile[(4*g+1)*104 + c] = f2bs(v.y);
        tile[(4*g+2)*104 + c] = f2bs(v.z);
        tile[(4*g+3)*104 + c] = f2bs(v.w);
    }
    __syncthreads();
    for (int e = tid; e < 64*12; e += 256) {
        int px = e / 12, c8 = e % 12;
        bfrag v = *(const bfrag*)(tile + px*104 + c8*8);
        *(bfrag*)(xb16 + ((size_t)(pix0 + px))*96 + c8*8) = v;
    }
}

// ---------------------------------------------------------------------------
// Repack weights to bf16 MFMA B-frag layouts (k = tap*96 + c):
//   wB1 (864x96): dconv_w   wB2 (864x32, o<18): off_w   wB (864x96): def_w
//   order: w[((s*NT+nt)*64 + l)*8 + j] = B[k=32s+(l>>4)*8+j][o=16nt+(l&15)]
// ---------------------------------------------------------------------------
__global__ void k_repack(const float* __restrict__ dconv_w,
                         const float* __restrict__ off_w,
                         const float* __restrict__ def_w,
                         short* __restrict__ wB1,
                         short* __restrict__ wB2,
                         short* __restrict__ wB) {
    int t = blockIdx.x * blockDim.x + threadIdx.x;
    if (t < 27648) {              // 864 x 32, NT=2
        int j = t & 7; int l = (t >> 3) & 63; int tile = t >> 9;
        int s = tile >> 1, nt = tile & 1;
        int k = 32*s + (l >> 4)*8 + j;
        int o = 16*nt + (l & 15);
        int c = k % 96, tap = k / 96;
        wB2[t] = (o < 18) ? f2bs(off_w[(o*96 + c)*9 + tap]) : (short)0;
    }
    if (t < 82944) {              // 864 x 96, NT=6
        int j = t & 7; int l = (t >> 3) & 63; int tile = t >> 9;
        int s = tile / 6, nt = tile % 6;
        int k = 32*s + (l >> 4)*8 + j;
        int o = 16*nt + (l & 15);
        int c = k % 96, tap = k / 96;
        wB1[t] = f2bs(dconv_w[(o*96 + c)*9 + tap]);
        wB[t]  = f2bs(def_w [(o*96 + c)*9 + tap]);
    }
}

#define SLICE_SHORTS 9216      // 18 KB per 6-nt tap slice (3 sc x 6 nt x 1 KB)

// ---------------------------------------------------------------------------
// Kernel 1 (M=32/wave, LDS weights, LDS-transposed epilogue).
// Block = 512 thr (8 waves), 256 px; grid 256.
// ---------------------------------------------------------------------------
__global__ __launch_bounds__(512, 2) void k_conv1(const float* __restrict__ x,
                                                  const short* __restrict__ xb16,
                                                  const short* __restrict__ wB,
                                                  const float* __restrict__ bias,
                                                  short* __restrict__ x3b) {
    __shared__ short wbuf[2][SLICE_SHORTS];       // 36 KB

    int pix0 = swizzle256(blockIdx.x) * 256;
    int b = pix0 / HWD; int hw0 = pix0 % HWD;
    int h0 = hw0 / WD;                            // block = 2 image rows
    int tid = threadIdx.x;
    int l = tid & 63, wv = tid >> 6;
    int q = l >> 4, mr = l & 15;
    const char* xbc = (const char*)(xb16 + ((size_t)b * HWD) * 96);
    const bfrag az = {0,0,0,0,0,0,0,0};

    int lpb[2], yb[2], wbx[2];
    #pragma unroll
    for (int mt = 0; mt < 2; mt++) {
        lpb[mt] = 32*wv + 16*mt;
        yb[mt]  = h0 + (lpb[mt] >> 7);
        wbx[mt] = (lpb[mt] & 127) + mr;
    }

    // prologue: stage slice 0
    {
        bfrag s0, s1, s2;
        int c2 = tid + 1024;
        s0 = *(const bfrag*)(wB + tid*8);
        s1 = *(const bfrag*)(wB + (tid+512)*8);
        if (c2 < 1152) s2 = *(const bfrag*)(wB + c2*8);
        *(bfrag*)&wbuf[0][tid*8]       = s0;
        *(bfrag*)&wbuf[0][(tid+512)*8] = s1;
        if (c2 < 1152) *(bfrag*)&wbuf[0][c2*8] = s2;
    }
    __syncthreads();

    ffrag acc[2][6];
    #pragma unroll
    for (int mt = 0; mt < 2; mt++)
        #pragma unroll
        for (int nt = 0; nt < 6; nt++) acc[mt][nt] = ffrag{0.f,0.f,0.f,0.f};

    int cur = 0;
    #pragma unroll 1
    for (int tap = 0; tap < 9; tap++) {
        bfrag s0, s1, s2;
        if (tap < 8) {
            const short* src = wB + (size_t)(tap+1)*SLICE_SHORTS;
            int c2 = tid + 1024;
            s0 = *(const bfrag*)(src + tid*8);
            s1 = *(const bfrag*)(src + (tid+512)*8);
            if (c2 < 1152) s2 = *(const bfrag*)(src + c2*8);
        }

        int ty = (tap/3)*2 - 2, tx = (tap%3)*2 - 2;
        #pragma unroll
        for (int mt = 0; mt < 2; mt++) {
            int y = yb[mt] + ty;
            bool vy = (unsigned)y < HD;
            int yc = min(max(y, 0), HD-1);
            int xx = wbx[mt] + tx;
            int xxc = min(max(xx, 0), WD-1);
            bool v = vy && ((unsigned)xx < WD);
            unsigned aoff = (unsigned)(((yc*WD + xxc)*96 + q*8) * 2);
            #pragma unroll
            for (int sc = 0; sc < 3; sc++) {
                bfrag a = *(const bfrag*)(xbc + aoff + sc*64);
                if (!v) a = az;
                const short* wp = &wbuf[cur][(sc*6)*512 + l*8];
                #pragma unroll
                for (int nt = 0; nt < 6; nt++) {
                    bfrag bb = *(const bfrag*)(wp + nt*512);
                    acc[mt][nt] = __builtin_amdgcn_mfma_f32_16x16x32_bf16(a, bb, acc[mt][nt], 0, 0, 0);
                }
            }
        }

        if (tap < 8) {
            int c2 = tid + 1024;
            *(bfrag*)&wbuf[cur^1][tid*8]       = s0;
            *(bfrag*)&wbuf[cur^1][(tid+512)*8] = s1;
            if (c2 < 1152) *(bfrag*)&wbuf[cur^1][c2*8] = s2;
        }
        __syncthreads();
        cur ^= 1;
    }

    // ---- epilogue: acc (+x, relu) -> LDS transpose tile -> coalesced bfrag
    // stores (48 scattered 2B stores/lane -> 3x 16B stores/thread/half).
    // wbuf is dead after the final tap barrier.
    short (*etile)[104] = (short(*)[104])&wbuf[0][0];   // 128 x 104 = 26.6 KB
    #pragma unroll 1
    for (int ph = 0; ph < 2; ph++) {
        #pragma unroll
        for (int mt = 0; mt < 2; mt++) {
            if ((lpb[mt] >> 7) == ph) {
                int lrow = (lpb[mt] & 127) + q*4;
                int hwb = hw0 + 128*ph + lrow;
                #pragma unroll
                for (int nt = 0; nt < 6; nt++) {
                    int o = 16*nt + mr;
                    float bo = bias[o];
                    float4 xr = *(const float4*)(x + ((size_t)(b*96 + o))*HWD + hwb);
                    etile[lrow+0][o] = f2bs(xr.x + fmaxf(acc[mt][nt][0] + bo, 0.f));
                    etile[lrow+1][o] = f2bs(xr.y + fmaxf(acc[mt][nt][1] + bo, 0.f));
                    etile[lrow+2][o] = f2bs(xr.z + fmaxf(acc[mt][nt][2] + bo, 0.f));
                    etile[lrow+3][o] = f2bs(xr.w + fmaxf(acc[mt][nt][3] + bo, 0.f));
                }
            }
        }
        __syncthreads();
        for (int e = tid; e < 128*12; e += 512) {
            int px = e / 12, c8 = e % 12;
            bfrag v = *(const bfrag*)&etile[px][c8*8];
            *(bfrag*)(x3b + ((size_t)(b*HWD + hw0 + 128*ph + px))*96 + c8*8) = v;
        }
        __syncthreads();
    }
}

// ---------------------------------------------------------------------------
// Kernel 2 (fused): conv2-MFMA with LDS-staged B slices (aliased with offsb,
// phases ordered by the tap-8 barrier) -> offsb -> gather with ONE-TAP-AHEAD
// corner prefetch (addresses + sc=0 data issued at tap top, consumed next
// tap: hides the ~370cy serial head under interp+MFMA) -> deform MFMA with
// LDS B slices -> out.  Block = 512 thr, 256 px, grid 256.
// ---------------------------------------------------------------------------
__global__ __launch_bounds__(512, 2) void k_deform(const short* __restrict__ x3b,
                                                   const short* __restrict__ wB2,
                                                   const float* __restrict__ off_b,
                                                   const short* __restrict__ wB,
                                                   const float* __restrict__ def_b,
                                                   float* __restrict__ out) {
    // 36 KB deform-weight dbuf | 20 KB region2 (conv2-B dbuf 12 KB, THEN offsb)
    __shared__ __align__(16) char smem[36864 + 20480];
    short (*wbuf)[SLICE_SHORTS] = (short(*)[SLICE_SHORTS])smem;
    short* cb = (short*)(smem + 36864);                 // [2][3072]
    float (*offsb)[20] = (float(*)[20])(smem + 36864);  // 256 x 20

    int pix0 = swizzle256(blockIdx.x) * 256;
    int b = pix0 / HWD; int hw0 = pix0 % HWD;
    int h0 = hw0 / WD;
    int tid = threadIdx.x;
    int l = tid & 63, wv = tid >> 6;
    int q = l >> 4, mr = l & 15;
    const char* xbc = (const char*)(x3b + ((size_t)b * HWD) * 96);
    const bfrag az = {0,0,0,0,0,0,0,0};

    int lpb[2], yb[2], wbx[2];
    #pragma unroll
    for (int mt = 0; mt < 2; mt++) {
        lpb[mt] = 32*wv + 16*mt;
        yb[mt]  = h0 + (lpb[mt] >> 7);
        wbx[mt] = (lpb[mt] & 127) + mr;
    }

    // prologue: stage deform slice 0 into wbuf[0], conv2-B slice 0 into cb[0]
    {
        bfrag s0, s1, s2;
        int c2 = tid + 1024;
        s0 = *(const bfrag*)(wB + tid*8);
        s1 = *(const bfrag*)(wB + (tid+512)*8);
        if (c2 < 1152) s2 = *(const bfrag*)(wB + c2*8);
        *(bfrag*)&wbuf[0][tid*8]       = s0;
        *(bfrag*)&wbuf[0][(tid+512)*8] = s1;
        if (c2 < 1152) *(bfrag*)&wbuf[0][c2*8] = s2;
        if (tid < 384) {
            bfrag sc2 = *(const bfrag*)(wB2 + tid*8);
            *(bfrag*)&cb[tid*8] = sc2;
        }
    }
    __syncthreads();

    // ---- conv2 via MFMA, B from LDS (dbuf 6 KB slices) ----
    ffrag oa[2][2];
    #pragma unroll
    for (int mt = 0; mt < 2; mt++)
        #pragma unroll
        for (int nt = 0; nt < 2; nt++) oa[mt][nt] = ffrag{0.f,0.f,0.f,0.f};

    int c2cur = 0;
    #pragma unroll 1
    for (int tap = 0; tap < 9; tap++) {
        bfrag sn;
        bool act = (tid < 384) && (tap < 8);
        if (act) sn = *(const bfrag*)(wB2 + (size_t)(tap+1)*3072 + tid*8);

        int ty = tap/3 - 1, tx = tap%3 - 1;
        #pragma unroll
        for (int mt = 0; mt < 2; mt++) {
            int y = yb[mt] + ty;
            bool vy = (unsigned)y < HD;
            int yc = min(max(y, 0), HD-1);
            int xx = wbx[mt] + tx;
            int xxc = min(max(xx, 0), WD-1);
            bool v = vy && ((unsigned)xx < WD);
            unsigned aoff = (unsigned)(((yc*WD + xxc)*96 + q*8) * 2);
            #pragma unroll
            for (int sc = 0; sc < 3; sc++) {
                const short* wb = cb + c2cur*3072 + (sc*2)*512 + l*8;
                bfrag b0 = *(const bfrag*)(wb);
                bfrag b1 = *(const bfrag*)(wb + 512);
                bfrag a = *(const bfrag*)(xbc + aoff + sc*64);
                if (!v) a = az;
                oa[mt][0] = __builtin_amdgcn_mfma_f32_16x16x32_bf16(a, b0, oa[mt][0], 0, 0, 0);
                oa[mt][1] = __builtin_amdgcn_mfma_f32_16x16x32_bf16(a, b1, oa[mt][1], 0, 0, 0);
            }
        }

        if (act) *(bfrag*)&cb[(c2cur^1)*3072 + tid*8] = sn;
        __syncthreads();               // also orders last cb reads vs offsb writes
        c2cur ^= 1;
    }

    // region2 now becomes offsb (all cb reads completed at the tap-8 barrier)
    #pragma unroll
    for (int mt = 0; mt < 2; mt++) {
        int row = lpb[mt] + q*4;
        float bo0 = off_b[mr];
        #pragma unroll
        for (int r = 0; r < 4; r++) offsb[row + r][mr] = oa[mt][0][r] + bo0;
        if (mr < 2) {
            float bo1 = off_b[16 + mr];
            #pragma unroll
            for (int r = 0; r < 4; r++) offsb[row + r][16 + mr] = oa[mt][1][r] + bo1;
        }
    }
    // no barrier: offsb rows 32wv..32wv+31 produced & consumed by wave wv

    // ---- gather + deform MFMA, one-tap-ahead corner prefetch ----
    ffrag acc[2][6];
    #pragma unroll
    for (int mt = 0; mt < 2; mt++)
        #pragma unroll
        for (int nt = 0; nt < 6; nt++) acc[mt][nt] = ffrag{0.f,0.f,0.f,0.f};

    // per-tap address/weight prep from offsb
    auto prep = [&](int tap, unsigned (&po)[2][4], float (&fbv)[2][4]) {
        #pragma unroll
        for (int mt = 0; mt < 2; mt++) {
            int lp = lpb[mt] + mr;
            float dy = offsb[lp][2*tap];
            float dx = offsb[lp][2*tap + 1];
            float py  = (float)(yb[mt]  + tap/3 - 1) + dy;
            float pxf = (float)(wbx[mt] + tap%3 - 1) + dx;
            float y0f = floorf(py), x0f = floorf(pxf);
            float wy = py - y0f, wx = pxf - x0f;
            int y0 = (int)y0f, x0 = (int)x0f;
            int y1 = y0 + 1, x1 = x0 + 1;
            bool vy0 = (unsigned)y0 < HD, vy1 = (unsigned)y1 < HD;
            bool vx0 = (unsigned)x0 < WD, vx1 = (unsigned)x1 < WD;
            fbv[mt][0] = (vy0 && vx0) ? (1.f-wy)*(1.f-wx) : 0.f;
            fbv[mt][1] = (vy0 && vx1) ? (1.f-wy)*wx       : 0.f;
            fbv[mt][2] = (vy1 && vx0) ? wy*(1.f-wx)       : 0.f;
            fbv[mt][3] = (vy1 && vx1) ? wy*wx             : 0.f;
            int yc0 = min(max(y0,0),HD-1), yc1 = min(max(y1,0),HD-1);
            int xc0 = min(max(x0,0),WD-1), xc1 = min(max(x1,0),WD-1);
            po[mt][0] = (unsigned)(((yc0*WD + xc0)*96 + q*8)*2);
            po[mt][1] = (unsigned)(((yc0*WD + xc1)*96 + q*8)*2);
            po[mt][2] = (unsigned)(((yc1*WD + xc0)*96 + q*8)*2);
            po[mt][3] = (unsigned)(((yc1*WD + xc1)*96 + q*8)*2);
        }
    };

    unsigned po[2][4]; float fbv[2][4];
    prep(0, po, fbv);
    bfrag cpre[8];
    #pragma unroll
    for (int mt = 0; mt < 2; mt++)
        #pragma unroll
        for (int k = 0; k < 4; k++)
            cpre[mt*4+k] = *(const bfrag*)(xbc + po[mt][k]);

    int cur = 0;
    #pragma unroll 1
    for (int tap = 0; tap < 9; tap++) {
        // (i) next deform-weight slice -> regs
        bfrag s0, s1, s2;
        if (tap < 8) {
            const short* src = wB + (size_t)(tap+1)*SLICE_SHORTS;
            int c2 = tid + 1024;
            s0 = *(const bfrag*)(src + tid*8);
            s1 = *(const bfrag*)(src + (tid+512)*8);
            if (c2 < 1152) s2 = *(const bfrag*)(src + c2*8);
        }
        // (ii) next tap addresses + sc=0 corner prefetch
        unsigned pon[2][4]; float fbn[2][4]; bfrag cnx[8];
        if (tap < 8) {
            prep(tap+1, pon, fbn);
            #pragma unroll
            for (int mt = 0; mt < 2; mt++)
                #pragma unroll
                for (int k = 0; k < 4; k++)
                    cnx[mt*4+k] = *(const bfrag*)(xbc + pon[mt][k]);
        }
        // (iii) sc = 0 from the prefetched corners
        {
            const short* wp = &wbuf[cur][0*512 + l*8];
            bfrag bbf[6];
            #pragma unroll
            for (int nt = 0; nt < 6; nt++) bbf[nt] = *(const bfrag*)(wp + nt*512);
            #pragma unroll
            for (int mt = 0; mt < 2; mt++) {
                bfrag a = interp4(cpre[mt*4+0], cpre[mt*4+1], cpre[mt*4+2], cpre[mt*4+3],
                                  fbv[mt][0], fbv[mt][1], fbv[mt][2], fbv[mt][3]);
                #pragma unroll
                for (int nt = 0; nt < 6; nt++)
                    acc[mt][nt] = __builtin_amdgcn_mfma_f32_16x16x32_bf16(a, bbf[nt], acc[mt][nt], 0, 0, 0);
            }
        }
        // sc = 1, 2 inline (addresses ready since tap top -> scheduler can hoist)
        #pragma unroll
        for (int sc = 1; sc < 3; sc++) {
            const short* wp = &wbuf[cur][(sc*6)*512 + l*8];
            bfrag bbf[6];
            #pragma unroll
            for (int nt = 0; nt < 6; nt++) bbf[nt] = *(const bfrag*)(wp + nt*512);
            #pragma unroll
            for (int mt = 0; mt < 2; mt++) {
                bfrag c00 = *(const bfrag*)(xbc + po[mt][0] + sc*64);
                bfrag c01 = *(const bfrag*)(xbc + po[mt][1] + sc*64);
                bfrag c10 = *(const bfrag*)(xbc + po[mt][2] + sc*64);
                bfrag c11 = *(const bfrag*)(xbc + po[mt][3] + sc*64);
                bfrag a = interp4(c00, c01, c10, c11,
                                  fbv[mt][0], fbv[mt][1], fbv[mt][2], fbv[mt][3]);
                #pragma unroll
                for (int nt = 0; nt < 6; nt++)
                    acc[mt][nt] = __builtin_amdgcn_mfma_f32_16x16x32_bf16(a, bbf[nt], acc[mt][nt], 0, 0, 0);
            }
        }
        // (iv) slice write + state advance
        if (tap < 8) {
            int c2 = tid + 1024;
            *(bfrag*)&wbuf[cur^1][tid*8]       = s0;
            *(bfrag*)&wbuf[cur^1][(tid+512)*8] = s1;
            if (c2 < 1152) *(bfrag*)&wbuf[cur^1][c2*8] = s2;
            #pragma unroll
            for (int mt = 0; mt < 2; mt++)
                #pragma unroll
                for (int k = 0; k < 4; k++) {
                    po[mt][k] = pon[mt][k];
                    fbv[mt][k] = fbn[mt][k];
                }
            #pragma unroll
            for (int k = 0; k < 8; k++) cpre[k] = cnx[k];
        }
        __syncthreads();
        cur ^= 1;
    }

    // ---- epilogue: NCHW fp32 out, float4 per (m-tile, n-tile) ----
    #pragma unroll
    for (int mt = 0; mt < 2; mt++) {
        int hwb = hw0 + lpb[mt] + q*4;
        #pragma unroll
        for (int nt = 0; nt < 6; nt++) {
            int o = 16*nt + mr;
            float bo = def_b[o];
            float4 v;
            v.x = acc[mt][nt][0] + bo; v.y = acc[mt][nt][1] + bo;
            v.z = acc[mt][nt][2] + bo; v.w = acc[mt][nt][3] + bo;
            *(float4*)(out + ((size_t)(b*96 + o))*HWD + hwb) = v;
        }
    }
}

// ---------------------------------------------------------------------------
// Workspace layout (bytes):
//   xb16 : 0        .. 12582912   (B*HW*96 bf16, NHWC of x)
//   x3b  : 12582912 .. 25165824   (B*HW*96 bf16, NHWC of x3)
//   wB1  : 25165824 .. 25331712
//   wB2  : 25331712 .. 25387008
//   wB   : 25387008 .. 25552896
// ---------------------------------------------------------------------------
extern "C" void kernel_launch(void* const* d_in, const int* in_sizes, int n_in,
                              void* d_out, int out_size, void* d_ws, size_t ws_size,
                              hipStream_t stream) {
    const float* x       = (const float*)d_in[0];
    const float* dconv_w = (const float*)d_in[1];
    const float* dconv_b = (const float*)d_in[2];
    const float* off_w   = (const float*)d_in[3];
    const float* off_b   = (const float*)d_in[4];
    const float* def_w   = (const float*)d_in[5];
    const float* def_b   = (const float*)d_in[6];
    float* out = (float*)d_out;

    char* ws = (char*)d_ws;
    short* xb16 = (short*)(ws);
    short* x3b  = (short*)(ws + 12582912);
    short* wB1  = (short*)(ws + 25165824);
    short* wB2  = (short*)(ws + 25331712);
    short* wB   = (short*)(ws + 25387008);

    k_repack<<<324, 256, 0, stream>>>(dconv_w, off_w, def_w, wB1, wB2, wB);
    k_transpose<<<(BD*HWD)/64, 256, 0, stream>>>(x, xb16);
    k_conv1<<<(BD*HWD)/256, 512, 0, stream>>>(x, xb16, wB1, dconv_b, x3b);
    k_deform<<<(BD*HWD)/256, 512, 0, stream>>>(x3b, wB2, off_b, wB, def_b, out);
}

// Round 8
// 160.656 us; speedup vs baseline: 1.0466x; 1.0466x over previous
//
#include <hip/hip_runtime.h>
#include <hip/hip_bf16.h>

#define BD 4
#define CD 96
#define OD 96
#define HD 128
#define WD 128
#define HWD (HD*WD)          // 16384

typedef __attribute__((ext_vector_type(8))) short bfrag;   // 8 bf16 (4 VGPRs)
typedef __attribute__((ext_vector_type(4))) float ffrag;   // 4 fp32 acc

__device__ __forceinline__ short f2bs(float f) {
    __hip_bfloat16 h = __float2bfloat16(f);
    return *reinterpret_cast<short*>(&h);
}

// bilinear combine of 4 corner channel-fragments -> bf16 A-fragment
__device__ __forceinline__ bfrag interp4(bfrag c00, bfrag c01, bfrag c10, bfrag c11,
                                         float f00, float f01, float f10, float f11) {
    const int* i00 = (const int*)&c00;
    const int* i01 = (const int*)&c01;
    const int* i10 = (const int*)&c10;
    const int* i11 = (const int*)&c11;
    int ap[4];
    #pragma unroll
    for (int d = 0; d < 4; d++) {
        float a0 = __int_as_float(((unsigned)i00[d]) << 16);
        float b0 = __int_as_float(((unsigned)i01[d]) << 16);
        float c0 = __int_as_float(((unsigned)i10[d]) << 16);
        float d0 = __int_as_float(((unsigned)i11[d]) << 16);
        float a1 = __int_as_float(i00[d] & 0xffff0000);
        float b1 = __int_as_float(i01[d] & 0xffff0000);
        float c1 = __int_as_float(i10[d] & 0xffff0000);
        float d1 = __int_as_float(i11[d] & 0xffff0000);
        float rlo = f00*a0 + f01*b0 + f10*c0 + f11*d0;
        float rhi = f00*a1 + f01*b1 + f10*c1 + f11*d1;
        ap[d] = (int)((unsigned short)f2bs(rlo)) |
                ((int)((unsigned short)f2bs(rhi)) << 16);
    }
    return *(const bfrag*)ap;
}

// XCD-aware swizzle for 512-block grids: XCD k owns 64 consecutive logical
// blocks = 64 consecutive rows (half an image) -> halos stay in its L2.
__device__ __forceinline__ int swizzle512(int gid) {
    return ((gid & 7) << 6) | (gid >> 3);
}

// ---------------------------------------------------------------------------
// Transpose: x (NCHW fp32) -> xb16 (pixel-major NHWC bf16). 64 px/block.
// ---------------------------------------------------------------------------
__global__ __launch_bounds__(256) void k_transpose(const float* __restrict__ x,
                                                   short* __restrict__ xb16) {
    __shared__ short tile[64 * 104];
    int pix0 = blockIdx.x * 64;
    int b = pix0 / HWD; int hw0 = pix0 % HWD;
    int tid = threadIdx.x;

    for (int e = tid; e < 96*16; e += 256) {
        int c = e >> 4, g = e & 15;
        float4 v = *(const float4*)(x + ((size_t)(b*96 + c))*HWD + hw0 + 4*g);
        tile[(4*g+0)*104 + c] = f2bs(v.x);
        tile[(4*g+1)*104 + c] = f2bs(v.y);
        tile[(4*g+2)*104 + c] = f2bs(v.z);
        tile[(4*g+3)*104 + c] = f2bs(v.w);
    }
    __syncthreads();
    for (int e = tid; e < 64*12; e += 256) {
        int px = e / 12, c8 = e % 12;
        bfrag v = *(const bfrag*)(tile + px*104 + c8*8);
        *(bfrag*)(xb16 + ((size_t)(pix0 + px))*96 + c8*8) = v;
    }
}

// ---------------------------------------------------------------------------
// Repack weights to bf16 MFMA B-frag layouts (k = tap*96 + c):
//   wB1 (864x96): dconv_w   wB2 (864x32, o<18): off_w   wB (864x96): def_w
//   order: w[((s*NT+nt)*64 + l)*8 + j] = B[k=32s+(l>>4)*8+j][o=16nt+(l&15)]
// ---------------------------------------------------------------------------
__global__ void k_repack(const float* __restrict__ dconv_w,
                         const float* __restrict__ off_w,
                         const float* __restrict__ def_w,
                         short* __restrict__ wB1,
                         short* __restrict__ wB2,
                         short* __restrict__ wB) {
    int t = blockIdx.x * blockDim.x + threadIdx.x;
    if (t < 27648) {              // 864 x 32, NT=2
        int j = t & 7; int l = (t >> 3) & 63; int tile = t >> 9;
        int s = tile >> 1, nt = tile & 1;
        int k = 32*s + (l >> 4)*8 + j;
        int o = 16*nt + (l & 15);
        int c = k % 96, tap = k / 96;
        wB2[t] = (o < 18) ? f2bs(off_w[(o*96 + c)*9 + tap]) : (short)0;
    }
    if (t < 82944) {              // 864 x 96, NT=6
        int j = t & 7; int l = (t >> 3) & 63; int tile = t >> 9;
        int s = tile / 6, nt = tile % 6;
        int k = 32*s + (l >> 4)*8 + j;
        int o = 16*nt + (l & 15);
        int c = k % 96, tap = k / 96;
        wB1[t] = f2bs(dconv_w[(o*96 + c)*9 + tap]);
        wB[t]  = f2bs(def_w [(o*96 + c)*9 + tap]);
    }
}

#define SLICE_SHORTS 9216      // 18 KB per 6-nt tap slice (3 sc x 6 nt x 1 KB)

// ---------------------------------------------------------------------------
// Kernel 1 (M=16/wave, LDS weights, LDS-transposed epilogue).
// Block = 512 thr (8 waves), 128 px = 1 row; wave owns 16 px, all 6 n-tiles
// (B from LDS -> M=16 is TA-line-neutral). Grid 512 -> 2 blocks/CU ->
// 4 waves/SIMD (vs round-6's 2): the latency-hiding axis.
// ---------------------------------------------------------------------------
__global__ __launch_bounds__(512, 2) void k_conv1(const float* __restrict__ x,
                                                  const short* __restrict__ xb16,
                                                  const short* __restrict__ wB,
                                                  const float* __restrict__ bias,
                                                  short* __restrict__ x3b) {
    __shared__ short wbuf[2][SLICE_SHORTS];       // 36 KB (2 blocks/CU: 72 KB)

    int pix0 = swizzle512(blockIdx.x) * 128;
    int b = pix0 / HWD; int hw0 = pix0 % HWD;
    int h = hw0 / WD;                             // block = 1 image row
    int tid = threadIdx.x;
    int l = tid & 63, wv = tid >> 6;
    int q = l >> 4, mr = l & 15;
    int px0w = 16*wv;                             // wave's pixel base in row
    const char* xbc = (const char*)(xb16 + ((size_t)b * HWD) * 96);
    const bfrag az = {0,0,0,0,0,0,0,0};

    // prologue: stage slice 0
    {
        bfrag s0, s1, s2;
        int c2 = tid + 1024;
        s0 = *(const bfrag*)(wB + tid*8);
        s1 = *(const bfrag*)(wB + (tid+512)*8);
        if (c2 < 1152) s2 = *(const bfrag*)(wB + c2*8);
        *(bfrag*)&wbuf[0][tid*8]       = s0;
        *(bfrag*)&wbuf[0][(tid+512)*8] = s1;
        if (c2 < 1152) *(bfrag*)&wbuf[0][c2*8] = s2;
    }
    __syncthreads();

    ffrag acc[6];
    #pragma unroll
    for (int nt = 0; nt < 6; nt++) acc[nt] = ffrag{0.f,0.f,0.f,0.f};

    int cur = 0;
    #pragma unroll 1
    for (int tap = 0; tap < 9; tap++) {
        bfrag s0, s1, s2;
        if (tap < 8) {
            const short* src = wB + (size_t)(tap+1)*SLICE_SHORTS;
            int c2 = tid + 1024;
            s0 = *(const bfrag*)(src + tid*8);
            s1 = *(const bfrag*)(src + (tid+512)*8);
            if (c2 < 1152) s2 = *(const bfrag*)(src + c2*8);
        }

        int y = h + (tap/3)*2 - 2;
        int yc = min(max(y, 0), HD-1);
        int xx = px0w + mr + (tap%3)*2 - 2;
        int xxc = min(max(xx, 0), WD-1);
        bool v = ((unsigned)y < HD) && ((unsigned)xx < WD);
        unsigned aoff = (unsigned)(((yc*WD + xxc)*96 + q*8) * 2);
        #pragma unroll
        for (int sc = 0; sc < 3; sc++) {
            bfrag a = *(const bfrag*)(xbc + aoff + sc*64);
            if (!v) a = az;
            const short* wp = &wbuf[cur][(sc*6)*512 + l*8];
            #pragma unroll
            for (int nt = 0; nt < 6; nt++) {
                bfrag bb = *(const bfrag*)(wp + nt*512);
                acc[nt] = __builtin_amdgcn_mfma_f32_16x16x32_bf16(a, bb, acc[nt], 0, 0, 0);
            }
        }

        if (tap < 8) {
            int c2 = tid + 1024;
            *(bfrag*)&wbuf[cur^1][tid*8]       = s0;
            *(bfrag*)&wbuf[cur^1][(tid+512)*8] = s1;
            if (c2 < 1152) *(bfrag*)&wbuf[cur^1][c2*8] = s2;
        }
        __syncthreads();
        cur ^= 1;
    }

    // ---- epilogue: acc (+x, relu) -> LDS transpose tile -> coalesced stores
    // (wbuf dead after the final tap barrier; 128x104 = 26.6 KB <= 36 KB)
    short (*etile)[104] = (short(*)[104])&wbuf[0][0];
    {
        int lrow = px0w + q*4;
        int hwb = hw0 + lrow;
        #pragma unroll
        for (int nt = 0; nt < 6; nt++) {
            int o = 16*nt + mr;
            float bo = bias[o];
            float4 xr = *(const float4*)(x + ((size_t)(b*96 + o))*HWD + hwb);
            etile[lrow+0][o] = f2bs(xr.x + fmaxf(acc[nt][0] + bo, 0.f));
            etile[lrow+1][o] = f2bs(xr.y + fmaxf(acc[nt][1] + bo, 0.f));
            etile[lrow+2][o] = f2bs(xr.z + fmaxf(acc[nt][2] + bo, 0.f));
            etile[lrow+3][o] = f2bs(xr.w + fmaxf(acc[nt][3] + bo, 0.f));
        }
    }
    __syncthreads();
    for (int e = tid; e < 128*12; e += 512) {
        int px = e / 12, c8 = e % 12;
        bfrag v = *(const bfrag*)&etile[px][c8*8];
        *(bfrag*)(x3b + ((size_t)(b*HWD + hw0 + px))*96 + c8*8) = v;
    }
}

// ---------------------------------------------------------------------------
// Kernel 2 (fused, M=16/wave): conv2-MFMA with LDS-staged B slices (aliased
// with offsb; ordered by the conv2 tap-8 barrier) -> offsb (wave-local rows,
// no barrier) -> gather + deform MFMA with LDS B slices (dbuf, 1 barrier/tap,
// NO corner prefetch).  Block = 512 thr, 128 px = 1 row; grid 512 ->
// 2 blocks/CU -> 4 waves/SIMD at round-6 per-pixel TA line count.
// ---------------------------------------------------------------------------
__global__ __launch_bounds__(512, 2) void k_deform(const short* __restrict__ x3b,
                                                   const short* __restrict__ wB2,
                                                   const float* __restrict__ off_b,
                                                   const short* __restrict__ wB,
                                                   const float* __restrict__ def_b,
                                                   float* __restrict__ out) {
    // 36 KB deform-weight dbuf | 12 KB region2 (conv2-B dbuf, THEN offsb 10 KB)
    __shared__ __align__(16) char smem[36864 + 12288];
    short (*wbuf)[SLICE_SHORTS] = (short(*)[SLICE_SHORTS])smem;
    short* cb = (short*)(smem + 36864);                 // [2][3072]
    float (*offsb)[20] = (float(*)[20])(smem + 36864);  // 128 x 20 = 10240 B

    int pix0 = swizzle512(blockIdx.x) * 128;
    int b = pix0 / HWD; int hw0 = pix0 % HWD;
    int h = hw0 / WD;                             // block = 1 image row
    int tid = threadIdx.x;
    int l = tid & 63, wv = tid >> 6;
    int q = l >> 4, mr = l & 15;
    int px0w = 16*wv;
    const char* xbc = (const char*)(x3b + ((size_t)b * HWD) * 96);
    const bfrag az = {0,0,0,0,0,0,0,0};

    // prologue: deform slice 0 -> wbuf[0], conv2-B slice 0 -> cb[0]
    {
        bfrag s0, s1, s2;
        int c2 = tid + 1024;
        s0 = *(const bfrag*)(wB + tid*8);
        s1 = *(const bfrag*)(wB + (tid+512)*8);
        if (c2 < 1152) s2 = *(const bfrag*)(wB + c2*8);
        *(bfrag*)&wbuf[0][tid*8]       = s0;
        *(bfrag*)&wbuf[0][(tid+512)*8] = s1;
        if (c2 < 1152) *(bfrag*)&wbuf[0][c2*8] = s2;
        if (tid < 384) {
            bfrag sc2 = *(const bfrag*)(wB2 + tid*8);
            *(bfrag*)&cb[tid*8] = sc2;
        }
    }
    __syncthreads();

    // ---- conv2 via MFMA, B from LDS (dbuf 6 KB slices) ----
    ffrag oa0 = ffrag{0.f,0.f,0.f,0.f};
    ffrag oa1 = ffrag{0.f,0.f,0.f,0.f};

    int c2cur = 0;
    #pragma unroll 1
    for (int tap = 0; tap < 9; tap++) {
        bfrag sn;
        bool act = (tid < 384) && (tap < 8);
        if (act) sn = *(const bfrag*)(wB2 + (size_t)(tap+1)*3072 + tid*8);

        int y = h + tap/3 - 1;
        int yc = min(max(y, 0), HD-1);
        int xx = px0w + mr + tap%3 - 1;
        int xxc = min(max(xx, 0), WD-1);
        bool v = ((unsigned)y < HD) && ((unsigned)xx < WD);
        unsigned aoff = (unsigned)(((yc*WD + xxc)*96 + q*8) * 2);
        #pragma unroll
        for (int sc = 0; sc < 3; sc++) {
            const short* wb = cb + c2cur*3072 + (sc*2)*512 + l*8;
            bfrag b0 = *(const bfrag*)(wb);
            bfrag b1 = *(const bfrag*)(wb + 512);
            bfrag a = *(const bfrag*)(xbc + aoff + sc*64);
            if (!v) a = az;
            oa0 = __builtin_amdgcn_mfma_f32_16x16x32_bf16(a, b0, oa0, 0, 0, 0);
            oa1 = __builtin_amdgcn_mfma_f32_16x16x32_bf16(a, b1, oa1, 0, 0, 0);
        }

        if (act) *(bfrag*)&cb[(c2cur^1)*3072 + tid*8] = sn;
        __syncthreads();               // orders last cb reads before offsb writes
        c2cur ^= 1;
    }

    // region2 becomes offsb (all cb reads done at the tap-8 barrier)
    {
        int row = px0w + q*4;
        float bo0 = off_b[mr];
        #pragma unroll
        for (int r = 0; r < 4; r++) offsb[row + r][mr] = oa0[r] + bo0;
        if (mr < 2) {
            float bo1 = off_b[16 + mr];
            #pragma unroll
            for (int r = 0; r < 4; r++) offsb[row + r][16 + mr] = oa1[r] + bo1;
        }
    }
    // no barrier: offsb rows px0w..px0w+15 produced & consumed by wave wv

    // ---- gather + deform MFMA (B from LDS, dbuf slices) ----
    ffrag acc[6];
    #pragma unroll
    for (int nt = 0; nt < 6; nt++) acc[nt] = ffrag{0.f,0.f,0.f,0.f};

    int cur = 0;
    #pragma unroll 1
    for (int tap = 0; tap < 9; tap++) {
        bfrag s0, s1, s2;
        if (tap < 8) {
            const short* src = wB + (size_t)(tap+1)*SLICE_SHORTS;
            int c2 = tid + 1024;
            s0 = *(const bfrag*)(src + tid*8);
            s1 = *(const bfrag*)(src + (tid+512)*8);
            if (c2 < 1152) s2 = *(const bfrag*)(src + c2*8);
        }

        unsigned po[4];
        float fbv[4];
        {
            int lp = px0w + mr;                // own pixel (row-local == global x)
            float dy = offsb[lp][2*tap];
            float dx = offsb[lp][2*tap + 1];
            float py  = (float)(h  + tap/3 - 1) + dy;
            float pxf = (float)(lp + tap%3 - 1) + dx;
            float y0f = floorf(py), x0f = floorf(pxf);
            float wy = py - y0f, wx = pxf - x0f;
            int y0 = (int)y0f, x0 = (int)x0f;
            int y1 = y0 + 1, x1 = x0 + 1;
            bool vy0 = (unsigned)y0 < HD, vy1 = (unsigned)y1 < HD;
            bool vx0 = (unsigned)x0 < WD, vx1 = (unsigned)x1 < WD;
            fbv[0] = (vy0 && vx0) ? (1.f-wy)*(1.f-wx) : 0.f;
            fbv[1] = (vy0 && vx1) ? (1.f-wy)*wx       : 0.f;
            fbv[2] = (vy1 && vx0) ? wy*(1.f-wx)       : 0.f;
            fbv[3] = (vy1 && vx1) ? wy*wx             : 0.f;
            int yc0 = min(max(y0,0),HD-1), yc1 = min(max(y1,0),HD-1);
            int xc0 = min(max(x0,0),WD-1), xc1 = min(max(x1,0),WD-1);
            po[0] = (unsigned)(((yc0*WD + xc0)*96 + q*8)*2);
            po[1] = (unsigned)(((yc0*WD + xc1)*96 + q*8)*2);
            po[2] = (unsigned)(((yc1*WD + xc0)*96 + q*8)*2);
            po[3] = (unsigned)(((yc1*WD + xc1)*96 + q*8)*2);
        }
        #pragma unroll
        for (int sc = 0; sc < 3; sc++) {
            const short* wp = &wbuf[cur][(sc*6)*512 + l*8];
            bfrag bbf[6];
            #pragma unroll
            for (int nt = 0; nt < 6; nt++) bbf[nt] = *(const bfrag*)(wp + nt*512);
            bfrag c00 = *(const bfrag*)(xbc + po[0] + sc*64);
            bfrag c01 = *(const bfrag*)(xbc + po[1] + sc*64);
            bfrag c10 = *(const bfrag*)(xbc + po[2] + sc*64);
            bfrag c11 = *(const bfrag*)(xbc + po[3] + sc*64);
            bfrag a = interp4(c00, c01, c10, c11, fbv[0], fbv[1], fbv[2], fbv[3]);
            #pragma unroll
            for (int nt = 0; nt < 6; nt++)
                acc[nt] = __builtin_amdgcn_mfma_f32_16x16x32_bf16(a, bbf[nt], acc[nt], 0, 0, 0);
        }

        if (tap < 8) {
            int c2 = tid + 1024;
            *(bfrag*)&wbuf[cur^1][tid*8]       = s0;
            *(bfrag*)&wbuf[cur^1][(tid+512)*8] = s1;
            if (c2 < 1152) *(bfrag*)&wbuf[cur^1][c2*8] = s2;
        }
        __syncthreads();
        cur ^= 1;
    }

    // ---- epilogue: NCHW fp32 out, float4 per n-tile ----
    int hwb = hw0 + px0w + q*4;
    #pragma unroll
    for (int nt = 0; nt < 6; nt++) {
        int o = 16*nt + mr;
        float bo = def_b[o];
        float4 v;
        v.x = acc[nt][0] + bo; v.y = acc[nt][1] + bo;
        v.z = acc[nt][2] + bo; v.w = acc[nt][3] + bo;
        *(float4*)(out + ((size_t)(b*96 + o))*HWD + hwb) = v;
    }
}

// ---------------------------------------------------------------------------
// Workspace layout (bytes):
//   xb16 : 0        .. 12582912   (B*HW*96 bf16, NHWC of x)
//   x3b  : 12582912 .. 25165824   (B*HW*96 bf16, NHWC of x3)
//   wB1  : 25165824 .. 25331712
//   wB2  : 25331712 .. 25387008
//   wB   : 25387008 .. 25552896
// ---------------------------------------------------------------------------
extern "C" void kernel_launch(void* const* d_in, const int* in_sizes, int n_in,
                              void* d_out, int out_size, void* d_ws, size_t ws_size,
                              hipStream_t stream) {
    const float* x       = (const float*)d_in[0];
    const float* dconv_w = (const float*)d_in[1];
    const float* dconv_b = (const float*)d_in[2];
    const float* off_w   = (const float*)d_in[3];
    const float* off_b   = (const float*)d_in[4];
    const float* def_w   = (const float*)d_in[5];
    const float* def_b   = (const float*)d_in[6];
    float* out = (float*)d_out;

    char* ws = (char*)d_ws;
    short* xb16 = (short*)(ws);
    short* x3b  = (short*)(ws + 12582912);
    short* wB1  = (short*)(ws + 25165824);
    short* wB2  = (short*)(ws + 25331712);
    short* wB   = (short*)(ws + 25387008);

    k_repack<<<324, 256, 0, stream>>>(dconv_w, off_w, def_w, wB1, wB2, wB);
    k_transpose<<<(BD*HWD)/64, 256, 0, stream>>>(x, xb16);
    k_conv1<<<(BD*HWD)/128, 512, 0, stream>>>(x, xb16, wB1, dconv_b, x3b);
    k_deform<<<(BD*HWD)/128, 512, 0, stream>>>(x3b, wB2, off_b, wB, def_b, out);
}

// Round 9
// 155.478 us; speedup vs baseline: 1.0815x; 1.0333x over previous
//
#include <hip/hip_runtime.h>
#include <hip/hip_bf16.h>

#define BD 4
#define CD 96
#define OD 96
#define HD 128
#define WD 128
#define HWD (HD*WD)          // 16384
#define PLANEB ((size_t)(BD*HWD)*64)   // bytes per sc-plane (32ch x 2B per px)

typedef __attribute__((ext_vector_type(8))) short bfrag;   // 8 bf16 (4 VGPRs)
typedef __attribute__((ext_vector_type(4))) float ffrag;   // 4 fp32 acc

__device__ __forceinline__ short f2bs(float f) {
    __hip_bfloat16 h = __float2bfloat16(f);
    return *reinterpret_cast<short*>(&h);
}

// bilinear combine of 4 corner channel-fragments -> bf16 A-fragment
__device__ __forceinline__ bfrag interp4(bfrag c00, bfrag c01, bfrag c10, bfrag c11,
                                         float f00, float f01, float f10, float f11) {
    const int* i00 = (const int*)&c00;
    const int* i01 = (const int*)&c01;
    const int* i10 = (const int*)&c10;
    const int* i11 = (const int*)&c11;
    int ap[4];
    #pragma unroll
    for (int d = 0; d < 4; d++) {
        float a0 = __int_as_float(((unsigned)i00[d]) << 16);
        float b0 = __int_as_float(((unsigned)i01[d]) << 16);
        float c0 = __int_as_float(((unsigned)i10[d]) << 16);
        float d0 = __int_as_float(((unsigned)i11[d]) << 16);
        float a1 = __int_as_float(i00[d] & 0xffff0000);
        float b1 = __int_as_float(i01[d] & 0xffff0000);
        float c1 = __int_as_float(i10[d] & 0xffff0000);
        float d1 = __int_as_float(i11[d] & 0xffff0000);
        float rlo = f00*a0 + f01*b0 + f10*c0 + f11*d0;
        float rhi = f00*a1 + f01*b1 + f10*c1 + f11*d1;
        ap[d] = (int)((unsigned short)f2bs(rlo)) |
                ((int)((unsigned short)f2bs(rhi)) << 16);
    }
    return *(const bfrag*)ap;
}

// XCD-aware swizzle for 512-block grids
__device__ __forceinline__ int swizzle512(int gid) {
    return ((gid & 7) << 6) | (gid >> 3);
}

// ---------------------------------------------------------------------------
// Transpose: x (NCHW fp32) -> xb16 in SC-PLANE layout:
//   plane sc (sc=ch/32) holds, per pixel, the 64B of channels sc*32..sc*32+31.
//   byte addr = sc*PLANEB + pix*64 + chunk*16  (chunk = (ch%32)/8)
// Conv A-reads become DENSE 1KB/wave (TA fast path); gather corners unchanged.
// ---------------------------------------------------------------------------
__global__ __launch_bounds__(256) void k_transpose(const float* __restrict__ x,
                                                   char* __restrict__ xbP) {
    __shared__ short tile[64 * 104];
    int pix0 = blockIdx.x * 64;
    int b = pix0 / HWD; int hw0 = pix0 % HWD;
    int tid = threadIdx.x;

    for (int e = tid; e < 96*16; e += 256) {
        int c = e >> 4, g = e & 15;
        float4 v = *(const float4*)(x + ((size_t)(b*96 + c))*HWD + hw0 + 4*g);
        tile[(4*g+0)*104 + c] = f2bs(v.x);
        tile[(4*g+1)*104 + c] = f2bs(v.y);
        tile[(4*g+2)*104 + c] = f2bs(v.z);
        tile[(4*g+3)*104 + c] = f2bs(v.w);
    }
    __syncthreads();
    for (int e = tid; e < 64*12; e += 256) {
        int px = e / 12, c8 = e % 12;
        int sc = c8 >> 2, ck = c8 & 3;          // channels 8*c8.. = sc*32+ck*8..
        bfrag v = *(const bfrag*)(tile + px*104 + c8*8);
        *(bfrag*)(xbP + (size_t)sc*PLANEB + ((size_t)(pix0 + px))*64 + ck*16) = v;
    }
}

// ---------------------------------------------------------------------------
// Repack weights to bf16 MFMA B-frag layouts (k = tap*96 + c):
//   wB1 (864x96): dconv_w   wB2 (864x32, o<18): off_w   wB (864x96): def_w
// ---------------------------------------------------------------------------
__global__ void k_repack(const float* __restrict__ dconv_w,
                         const float* __restrict__ off_w,
                         const float* __restrict__ def_w,
                         short* __restrict__ wB1,
                         short* __restrict__ wB2,
                         short* __restrict__ wB) {
    int t = blockIdx.x * blockDim.x + threadIdx.x;
    if (t < 27648) {              // 864 x 32, NT=2
        int j = t & 7; int l = (t >> 3) & 63; int tile = t >> 9;
        int s = tile >> 1, nt = tile & 1;
        int k = 32*s + (l >> 4)*8 + j;
        int o = 16*nt + (l & 15);
        int c = k % 96, tap = k / 96;
        wB2[t] = (o < 18) ? f2bs(off_w[(o*96 + c)*9 + tap]) : (short)0;
    }
    if (t < 82944) {              // 864 x 96, NT=6
        int j = t & 7; int l = (t >> 3) & 63; int tile = t >> 9;
        int s = tile / 6, nt = tile % 6;
        int k = 32*s + (l >> 4)*8 + j;
        int o = 16*nt + (l & 15);
        int c = k % 96, tap = k / 96;
        wB1[t] = f2bs(dconv_w[(o*96 + c)*9 + tap]);
        wB[t]  = f2bs(def_w [(o*96 + c)*9 + tap]);
    }
}

#define SLICE_SHORTS 9216      // 18 KB per 6-nt tap slice (3 sc x 6 nt x 1 KB)

// ---------------------------------------------------------------------------
// Kernel 1 (M=16/wave, LDS weights, sc-plane A-loads, plane-layout epilogue).
// Block = 512 thr (8 waves), 128 px = 1 row; grid 512 -> 2 blocks/CU.
// A-loads per (tap,sc): 64 lanes cover a dense 1KB span of one plane ->
// coalesced (was 16 scattered 64B segments).
// ---------------------------------------------------------------------------
__global__ __launch_bounds__(512, 2) void k_conv1(const float* __restrict__ x,
                                                  const char* __restrict__ xbP,
                                                  const short* __restrict__ wB,
                                                  const float* __restrict__ bias,
                                                  char* __restrict__ x3P) {
    __shared__ short wbuf[2][SLICE_SHORTS];       // 36 KB

    int pix0 = swizzle512(blockIdx.x) * 128;
    int b = pix0 / HWD; int hw0 = pix0 % HWD;
    int h = hw0 / WD;                             // block = 1 image row
    int tid = threadIdx.x;
    int l = tid & 63, wv = tid >> 6;
    int q = l >> 4, mr = l & 15;
    int px0w = 16*wv;
    const bfrag az = {0,0,0,0,0,0,0,0};

    // prologue: stage slice 0
    {
        bfrag s0, s1, s2;
        int c2 = tid + 1024;
        s0 = *(const bfrag*)(wB + tid*8);
        s1 = *(const bfrag*)(wB + (tid+512)*8);
        if (c2 < 1152) s2 = *(const bfrag*)(wB + c2*8);
        *(bfrag*)&wbuf[0][tid*8]       = s0;
        *(bfrag*)&wbuf[0][(tid+512)*8] = s1;
        if (c2 < 1152) *(bfrag*)&wbuf[0][c2*8] = s2;
    }
    __syncthreads();

    ffrag acc[6];
    #pragma unroll
    for (int nt = 0; nt < 6; nt++) acc[nt] = ffrag{0.f,0.f,0.f,0.f};

    int cur = 0;
    #pragma unroll 1
    for (int tap = 0; tap < 9; tap++) {
        bfrag s0, s1, s2;
        if (tap < 8) {
            const short* src = wB + (size_t)(tap+1)*SLICE_SHORTS;
            int c2 = tid + 1024;
            s0 = *(const bfrag*)(src + tid*8);
            s1 = *(const bfrag*)(src + (tid+512)*8);
            if (c2 < 1152) s2 = *(const bfrag*)(src + c2*8);
        }

        int y = h + (tap/3)*2 - 2;
        int yc = min(max(y, 0), HD-1);
        int xx = px0w + mr + (tap%3)*2 - 2;
        int xxc = min(max(xx, 0), WD-1);
        bool v = ((unsigned)y < HD) && ((unsigned)xx < WD);
        size_t u = ((size_t)(b*HWD + yc*WD + xxc))*64 + q*16;   // in-plane byte off
        #pragma unroll
        for (int sc = 0; sc < 3; sc++) {
            bfrag a = *(const bfrag*)(xbP + (size_t)sc*PLANEB + u);
            if (!v) a = az;
            const short* wp = &wbuf[cur][(sc*6)*512 + l*8];
            #pragma unroll
            for (int nt = 0; nt < 6; nt++) {
                bfrag bb = *(const bfrag*)(wp + nt*512);
                acc[nt] = __builtin_amdgcn_mfma_f32_16x16x32_bf16(a, bb, acc[nt], 0, 0, 0);
            }
        }

        if (tap < 8) {
            int c2 = tid + 1024;
            *(bfrag*)&wbuf[cur^1][tid*8]       = s0;
            *(bfrag*)&wbuf[cur^1][(tid+512)*8] = s1;
            if (c2 < 1152) *(bfrag*)&wbuf[cur^1][c2*8] = s2;
        }
        __syncthreads();
        cur ^= 1;
    }

    // ---- epilogue: acc (+x, relu) -> LDS transpose tile -> plane stores
    short (*etile)[104] = (short(*)[104])&wbuf[0][0];   // 128 x 104 = 26.6 KB
    {
        int lrow = px0w + q*4;
        int hwb = hw0 + lrow;
        #pragma unroll
        for (int nt = 0; nt < 6; nt++) {
            int o = 16*nt + mr;
            float bo = bias[o];
            float4 xr = *(const float4*)(x + ((size_t)(b*96 + o))*HWD + hwb);
            etile[lrow+0][o] = f2bs(xr.x + fmaxf(acc[nt][0] + bo, 0.f));
            etile[lrow+1][o] = f2bs(xr.y + fmaxf(acc[nt][1] + bo, 0.f));
            etile[lrow+2][o] = f2bs(xr.z + fmaxf(acc[nt][2] + bo, 0.f));
            etile[lrow+3][o] = f2bs(xr.w + fmaxf(acc[nt][3] + bo, 0.f));
        }
    }
    __syncthreads();
    for (int e = tid; e < 128*12; e += 512) {
        int px = e / 12, c8 = e % 12;
        int sc = c8 >> 2, ck = c8 & 3;
        bfrag v = *(const bfrag*)&etile[px][c8*8];
        *(bfrag*)(x3P + (size_t)sc*PLANEB + ((size_t)(b*HWD + hw0 + px))*64 + ck*16) = v;
    }
}

// ---------------------------------------------------------------------------
// Kernel 2 (fused, M=16/wave, sc-plane x3): conv2-MFMA (coalesced A, LDS B)
// -> offsb (wave-local, no barrier) -> gather (scattered floor, unchanged)
// + deform MFMA with LDS B slices.  Block = 512 thr, 128 px; grid 512.
// ---------------------------------------------------------------------------
__global__ __launch_bounds__(512, 2) void k_deform(const char* __restrict__ x3P,
                                                   const short* __restrict__ wB2,
                                                   const float* __restrict__ off_b,
                                                   const short* __restrict__ wB,
                                                   const float* __restrict__ def_b,
                                                   float* __restrict__ out) {
    // 36 KB deform-weight dbuf | 12 KB region2 (conv2-B dbuf, THEN offsb 10 KB)
    __shared__ __align__(16) char smem[36864 + 12288];
    short (*wbuf)[SLICE_SHORTS] = (short(*)[SLICE_SHORTS])smem;
    short* cb = (short*)(smem + 36864);                 // [2][3072]
    float (*offsb)[20] = (float(*)[20])(smem + 36864);  // 128 x 20 = 10240 B

    int pix0 = swizzle512(blockIdx.x) * 128;
    int b = pix0 / HWD; int hw0 = pix0 % HWD;
    int h = hw0 / WD;                             // block = 1 image row
    int tid = threadIdx.x;
    int l = tid & 63, wv = tid >> 6;
    int q = l >> 4, mr = l & 15;
    int px0w = 16*wv;
    const bfrag az = {0,0,0,0,0,0,0,0};

    // prologue: deform slice 0 -> wbuf[0], conv2-B slice 0 -> cb[0]
    {
        bfrag s0, s1, s2;
        int c2 = tid + 1024;
        s0 = *(const bfrag*)(wB + tid*8);
        s1 = *(const bfrag*)(wB + (tid+512)*8);
        if (c2 < 1152) s2 = *(const bfrag*)(wB + c2*8);
        *(bfrag*)&wbuf[0][tid*8]       = s0;
        *(bfrag*)&wbuf[0][(tid+512)*8] = s1;
        if (c2 < 1152) *(bfrag*)&wbuf[0][c2*8] = s2;
        if (tid < 384) {
            bfrag sc2 = *(const bfrag*)(wB2 + tid*8);
            *(bfrag*)&cb[tid*8] = sc2;
        }
    }
    __syncthreads();

    // ---- conv2 via MFMA, A coalesced from planes, B from LDS ----
    ffrag oa0 = ffrag{0.f,0.f,0.f,0.f};
    ffrag oa1 = ffrag{0.f,0.f,0.f,0.f};

    int c2cur = 0;
    #pragma unroll 1
    for (int tap = 0; tap < 9; tap++) {
        bfrag sn;
        bool act = (tid < 384) && (tap < 8);
        if (act) sn = *(const bfrag*)(wB2 + (size_t)(tap+1)*3072 + tid*8);

        int y = h + tap/3 - 1;
        int yc = min(max(y, 0), HD-1);
        int xx = px0w + mr + tap%3 - 1;
        int xxc = min(max(xx, 0), WD-1);
        bool v = ((unsigned)y < HD) && ((unsigned)xx < WD);
        size_t u = ((size_t)(b*HWD + yc*WD + xxc))*64 + q*16;
        #pragma unroll
        for (int sc = 0; sc < 3; sc++) {
            const short* wb = cb + c2cur*3072 + (sc*2)*512 + l*8;
            bfrag b0 = *(const bfrag*)(wb);
            bfrag b1 = *(const bfrag*)(wb + 512);
            bfrag a = *(const bfrag*)(x3P + (size_t)sc*PLANEB + u);
            if (!v) a = az;
            oa0 = __builtin_amdgcn_mfma_f32_16x16x32_bf16(a, b0, oa0, 0, 0, 0);
            oa1 = __builtin_amdgcn_mfma_f32_16x16x32_bf16(a, b1, oa1, 0, 0, 0);
        }

        if (act) *(bfrag*)&cb[(c2cur^1)*3072 + tid*8] = sn;
        __syncthreads();               // orders last cb reads before offsb writes
        c2cur ^= 1;
    }

    // region2 becomes offsb (all cb reads done at the tap-8 barrier)
    {
        int row = px0w + q*4;
        float bo0 = off_b[mr];
        #pragma unroll
        for (int r = 0; r < 4; r++) offsb[row + r][mr] = oa0[r] + bo0;
        if (mr < 2) {
            float bo1 = off_b[16 + mr];
            #pragma unroll
            for (int r = 0; r < 4; r++) offsb[row + r][16 + mr] = oa1[r] + bo1;
        }
    }
    // no barrier: offsb rows px0w..px0w+15 produced & consumed by wave wv

    // ---- gather + deform MFMA (B from LDS, dbuf slices) ----
    ffrag acc[6];
    #pragma unroll
    for (int nt = 0; nt < 6; nt++) acc[nt] = ffrag{0.f,0.f,0.f,0.f};

    int cur = 0;
    #pragma unroll 1
    for (int tap = 0; tap < 9; tap++) {
        bfrag s0, s1, s2;
        if (tap < 8) {
            const short* src = wB + (size_t)(tap+1)*SLICE_SHORTS;
            int c2 = tid + 1024;
            s0 = *(const bfrag*)(src + tid*8);
            s1 = *(const bfrag*)(src + (tid+512)*8);
            if (c2 < 1152) s2 = *(const bfrag*)(src + c2*8);
        }

        size_t po[4];
        float fbv[4];
        {
            int lp = px0w + mr;                // own pixel (row-local == global x)
            float dy = offsb[lp][2*tap];
            float dx = offsb[lp][2*tap + 1];
            float py  = (float)(h  + tap/3 - 1) + dy;
            float pxf = (float)(lp + tap%3 - 1) + dx;
            float y0f = floorf(py), x0f = floorf(pxf);
            float wy = py - y0f, wx = pxf - x0f;
            int y0 = (int)y0f, x0 = (int)x0f;
            int y1 = y0 + 1, x1 = x0 + 1;
            bool vy0 = (unsigned)y0 < HD, vy1 = (unsigned)y1 < HD;
            bool vx0 = (unsigned)x0 < WD, vx1 = (unsigned)x1 < WD;
            fbv[0] = (vy0 && vx0) ? (1.f-wy)*(1.f-wx) : 0.f;
            fbv[1] = (vy0 && vx1) ? (1.f-wy)*wx       : 0.f;
            fbv[2] = (vy1 && vx0) ? wy*(1.f-wx)       : 0.f;
            fbv[3] = (vy1 && vx1) ? wy*wx             : 0.f;
            int yc0 = min(max(y0,0),HD-1), yc1 = min(max(y1,0),HD-1);
            int xc0 = min(max(x0,0),WD-1), xc1 = min(max(x1,0),WD-1);
            po[0] = ((size_t)(b*HWD + yc0*WD + xc0))*64 + q*16;
            po[1] = ((size_t)(b*HWD + yc0*WD + xc1))*64 + q*16;
            po[2] = ((size_t)(b*HWD + yc1*WD + xc0))*64 + q*16;
            po[3] = ((size_t)(b*HWD + yc1*WD + xc1))*64 + q*16;
        }
        #pragma unroll
        for (int sc = 0; sc < 3; sc++) {
            const char* pb = x3P + (size_t)sc*PLANEB;
            const short* wp = &wbuf[cur][(sc*6)*512 + l*8];
            bfrag bbf[6];
            #pragma unroll
            for (int nt = 0; nt < 6; nt++) bbf[nt] = *(const bfrag*)(wp + nt*512);
            bfrag c00 = *(const bfrag*)(pb + po[0]);
            bfrag c01 = *(const bfrag*)(pb + po[1]);
            bfrag c10 = *(const bfrag*)(pb + po[2]);
            bfrag c11 = *(const bfrag*)(pb + po[3]);
            bfrag a = interp4(c00, c01, c10, c11, fbv[0], fbv[1], fbv[2], fbv[3]);
            #pragma unroll
            for (int nt = 0; nt < 6; nt++)
                acc[nt] = __builtin_amdgcn_mfma_f32_16x16x32_bf16(a, bbf[nt], acc[nt], 0, 0, 0);
        }

        if (tap < 8) {
            int c2 = tid + 1024;
            *(bfrag*)&wbuf[cur^1][tid*8]       = s0;
            *(bfrag*)&wbuf[cur^1][(tid+512)*8] = s1;
            if (c2 < 1152) *(bfrag*)&wbuf[cur^1][c2*8] = s2;
        }
        __syncthreads();
        cur ^= 1;
    }

    // ---- epilogue: NCHW fp32 out, float4 per n-tile (line-coalesced via q) ----
    int hwb = hw0 + px0w + q*4;
    #pragma unroll
    for (int nt = 0; nt < 6; nt++) {
        int o = 16*nt + mr;
        float bo = def_b[o];
        float4 v;
        v.x = acc[nt][0] + bo; v.y = acc[nt][1] + bo;
        v.z = acc[nt][2] + bo; v.w = acc[nt][3] + bo;
        *(float4*)(out + ((size_t)(b*96 + o))*HWD + hwb) = v;
    }
}

// ---------------------------------------------------------------------------
// Workspace layout (bytes):
//   xbP : 0        .. 12582912   (3 sc-planes x B*HW x 64B, bf16 of x)
//   x3P : 12582912 .. 25165824   (3 sc-planes of x3)
//   wB1 : 25165824 .. 25331712
//   wB2 : 25331712 .. 25387008
//   wB  : 25387008 .. 25552896
// ---------------------------------------------------------------------------
extern "C" void kernel_launch(void* const* d_in, const int* in_sizes, int n_in,
                              void* d_out, int out_size, void* d_ws, size_t ws_size,
                              hipStream_t stream) {
    const float* x       = (const float*)d_in[0];
    const float* dconv_w = (const float*)d_in[1];
    const float* dconv_b = (const float*)d_in[2];
    const float* off_w   = (const float*)d_in[3];
    const float* off_b   = (const float*)d_in[4];
    const float* def_w   = (const float*)d_in[5];
    const float* def_b   = (const float*)d_in[6];
    float* out = (float*)d_out;

    char* ws = (char*)d_ws;
    char*  xbP  = ws;
    char*  x3P  = ws + 12582912;
    short* wB1  = (short*)(ws + 25165824);
    short* wB2  = (short*)(ws + 25331712);
    short* wB   = (short*)(ws + 25387008);

    k_repack<<<324, 256, 0, stream>>>(dconv_w, off_w, def_w, wB1, wB2, wB);
    k_transpose<<<(BD*HWD)/64, 256, 0, stream>>>(x, xbP);
    k_conv1<<<(BD*HWD)/128, 512, 0, stream>>>(x, xbP, wB1, dconv_b, x3P);
    k_deform<<<(BD*HWD)/128, 512, 0, stream>>>(x3P, wB2, off_b, wB, def_b, out);
}